// Round 1
// baseline (1086.930 us; speedup 1.0000x reference)
//
#include <hip/hip_runtime.h>
#include <hip/hip_bf16.h>
#include <math.h>

// Problem constants (Qwen3 MoE block)
#define T_TOK 2048
#define H_DIM 2048
#define NEXP  64
#define TOPK  8
#define I_DIM 768
#define CAPE  512

typedef short bf16x8 __attribute__((ext_vector_type(8)));
typedef short bf16x4 __attribute__((ext_vector_type(4)));
typedef float f32x4  __attribute__((ext_vector_type(4)));

__device__ __forceinline__ unsigned short f2bf(float f) {
  unsigned u = __float_as_uint(f);
  u += 0x7fffu + ((u >> 16) & 1u);   // RNE
  return (unsigned short)(u >> 16);
}
__device__ __forceinline__ float bf2f(unsigned short b) {
  return __uint_as_float(((unsigned)b) << 16);
}
__device__ __forceinline__ unsigned pack2(float lo, float hi) {
  return (unsigned)f2bf(lo) | ((unsigned)f2bf(hi) << 16);
}

// ---------------- K1: router logits + softmax-top8 + renorm ----------------
// block = 256 (4 waves), each wave owns one token; lane = expert id.
__global__ __launch_bounds__(256) void k_router(const float* __restrict__ x,
                                                const float* __restrict__ wr,
                                                int* __restrict__ topk_idx,
                                                float* __restrict__ topk_w) {
  const int lane = threadIdx.x & 63;
  const int t = blockIdx.x * 4 + (threadIdx.x >> 6);
  const float4* xr   = (const float4*)(x + (size_t)t * H_DIM);
  const float4* wrow = (const float4*)(wr + (size_t)lane * H_DIM);
  double acc = 0.0;                      // fp64: minimize top-k tie risk
  for (int i = 0; i < H_DIM / 4; ++i) {
    float4 a = xr[i], b = wrow[i];
    acc += (double)a.x * b.x; acc += (double)a.y * b.y;
    acc += (double)a.z * b.z; acc += (double)a.w * b.w;
  }
  float cur = (float)acc;
  float val[TOPK]; int idx[TOPK];
#pragma unroll
  for (int r = 0; r < TOPK; ++r) {
    float bv = cur; int bi = lane;
#pragma unroll
    for (int off = 32; off > 0; off >>= 1) {   // argmax, ties -> lower index
      float ov = __shfl_xor(bv, off);
      int   oi = __shfl_xor(bi, off);
      if (ov > bv || (ov == bv && oi < bi)) { bv = ov; bi = oi; }
    }
    val[r] = bv; idx[r] = bi;
    if (lane == bi) cur = -INFINITY;
  }
  float m = val[0], s = 0.f, w[TOPK];
#pragma unroll
  for (int r = 0; r < TOPK; ++r) { w[r] = expf(val[r] - m); s += w[r]; }
  if (lane < TOPK) {
    topk_idx[t * TOPK + lane] = idx[lane];
    topk_w [t * TOPK + lane] = w[lane] / s;   // == softmax-then-renorm
  }
}

// ---------------- K2: stable rank within expert (counting sort semantics) --
// Single block, 256 threads, 64 chunks of 256 pairs; ballot-based rank.
__global__ __launch_bounds__(256) void k_rank(const int* __restrict__ topk_idx,
                                              int* __restrict__ pair_pos,
                                              int* __restrict__ slot_token,
                                              int* __restrict__ cnts) {
  __shared__ int s_run[64];
  __shared__ int s_whist[4][64];
  const int tid = threadIdx.x, lane = tid & 63, wv = tid >> 6;
  if (tid < 64) s_run[tid] = 0;
  for (int c = 0; c < 64; ++c) {
    const int p = c * 256 + tid;
    const int e = topk_idx[p];
    __syncthreads();                       // prior s_run update done
    s_whist[wv][lane] = 0;
    __syncthreads();
    unsigned long long m = ~0ull;          // lanes in this wave with same e
#pragma unroll
    for (int b = 0; b < 6; ++b) {
      unsigned long long bb = __ballot((e >> b) & 1);
      m &= ((e >> b) & 1) ? bb : ~bb;
    }
    const int rw = __popcll(m & ((1ull << lane) - 1ull));
    if (rw == 0) s_whist[wv][e] = __popcll(m);   // group leader writes count
    __syncthreads();
    int r = rw;
    for (int w2 = 0; w2 < wv; ++w2) r += s_whist[w2][e];
    const int pos = s_run[e] + r;          // stable rank within expert
    pair_pos[p] = pos;
    if (pos < CAPE) slot_token[e * CAPE + pos] = p >> 3;  // token id
    __syncthreads();
    if (tid < 64)
      s_run[tid] += s_whist[0][tid] + s_whist[1][tid] + s_whist[2][tid] + s_whist[3][tid];
  }
  __syncthreads();
  if (tid < 64) cnts[tid] = s_run[tid];
}

// ---------------- K3: fused gate+up GEMM + SwiGLU -> act (bf16) ------------
// grid = E * 6 (n-tiles of 128 over I=768); block = 512 (8 waves, 2x4).
// A gathered from x via slot_token (fp32->bf16), B transposed+packed to LDS.
__global__ __launch_bounds__(512) void k_gateup(const float* __restrict__ x,
                                                const float* __restrict__ wg,
                                                const float* __restrict__ wu,
                                                const int* __restrict__ slot_token,
                                                const int* __restrict__ cnts,
                                                unsigned short* __restrict__ act) {
  const int e = blockIdx.x / 6, nt = blockIdx.x % 6;
  int cnt = cnts[e]; cnt = cnt < CAPE ? cnt : CAPE;
  if (cnt <= 0) return;
  const int mtiles = (cnt + 127) >> 7;

  __shared__ __align__(16) short As[128 * 40];
  __shared__ __align__(16) short Bg[128 * 40];
  __shared__ __align__(16) short Bu[128 * 40];

  const int tid = threadIdx.x;
  const int lane = tid & 63, wave = tid >> 6;
  const int wm = wave >> 2, wn = wave & 3;       // 2x4 wave grid, 64x32 tiles
  const int lr = lane & 15, lg = lane >> 4;

  // A staging tasks: 1024 float4 tasks / 512 thr = 2 each
  const int a_row0 = tid >> 3, a_kq = tid & 7;
  const int a_row1 = a_row0 + 64;
  // B staging tasks: kp in [0,16) k-pairs, nq in [0,32) col-quads
  const int b_kp = (tid & 7) | ((tid >> 8) << 3);
  const int b_nq = (tid >> 3) & 31;
  const int bk = 2 * b_kp, bn = 4 * b_nq;
  const size_t wbase = (size_t)e * H_DIM * I_DIM + (size_t)nt * 128;

  for (int mt = 0; mt < mtiles; ++mt) {
    const int m0 = mt << 7;
    const int tok0 = (m0 + a_row0 < cnt) ? slot_token[e * CAPE + m0 + a_row0] : 0;
    const int tok1 = (m0 + a_row1 < cnt) ? slot_token[e * CAPE + m0 + a_row1] : 0;
    f32x4 accg[4][2], accu[4][2];
#pragma unroll
    for (int mi = 0; mi < 4; ++mi)
#pragma unroll
      for (int ni = 0; ni < 2; ++ni) {
        accg[mi][ni] = (f32x4){0.f, 0.f, 0.f, 0.f};
        accu[mi][ni] = (f32x4){0.f, 0.f, 0.f, 0.f};
      }

    for (int kt = 0; kt < H_DIM / 32; ++kt) {
      const int k0 = kt * 32;
      __syncthreads();
      { // A: gather x rows, cvt to bf16
        float4 v0 = *(const float4*)(x + (size_t)tok0 * H_DIM + k0 + a_kq * 4);
        float4 v1 = *(const float4*)(x + (size_t)tok1 * H_DIM + k0 + a_kq * 4);
        bf16x4 s0, s1;
        s0[0]=(short)f2bf(v0.x); s0[1]=(short)f2bf(v0.y); s0[2]=(short)f2bf(v0.z); s0[3]=(short)f2bf(v0.w);
        s1[0]=(short)f2bf(v1.x); s1[1]=(short)f2bf(v1.y); s1[2]=(short)f2bf(v1.z); s1[3]=(short)f2bf(v1.w);
        *(bf16x4*)(&As[a_row0 * 40 + a_kq * 4]) = s0;
        *(bf16x4*)(&As[a_row1 * 40 + a_kq * 4]) = s1;
      }
      { // B: load 2 rows x 4 cols, transpose-pack into Bt[n][k]
        const size_t rb = wbase + (size_t)(k0 + bk) * I_DIM + bn;
        float4 g0 = *(const float4*)(wg + rb);
        float4 g1 = *(const float4*)(wg + rb + I_DIM);
        float4 u0 = *(const float4*)(wu + rb);
        float4 u1 = *(const float4*)(wu + rb + I_DIM);
        *(unsigned*)(&Bg[(bn + 0) * 40 + bk]) = pack2(g0.x, g1.x);
        *(unsigned*)(&Bg[(bn + 1) * 40 + bk]) = pack2(g0.y, g1.y);
        *(unsigned*)(&Bg[(bn + 2) * 40 + bk]) = pack2(g0.z, g1.z);
        *(unsigned*)(&Bg[(bn + 3) * 40 + bk]) = pack2(g0.w, g1.w);
        *(unsigned*)(&Bu[(bn + 0) * 40 + bk]) = pack2(u0.x, u1.x);
        *(unsigned*)(&Bu[(bn + 1) * 40 + bk]) = pack2(u0.y, u1.y);
        *(unsigned*)(&Bu[(bn + 2) * 40 + bk]) = pack2(u0.z, u1.z);
        *(unsigned*)(&Bu[(bn + 3) * 40 + bk]) = pack2(u0.w, u1.w);
      }
      __syncthreads();
      bf16x8 a[4], bg[2], bu[2];
#pragma unroll
      for (int mi = 0; mi < 4; ++mi)
        a[mi] = *(const bf16x8*)(&As[(wm * 64 + mi * 16 + lr) * 40 + lg * 8]);
#pragma unroll
      for (int ni = 0; ni < 2; ++ni) {
        bg[ni] = *(const bf16x8*)(&Bg[(wn * 32 + ni * 16 + lr) * 40 + lg * 8]);
        bu[ni] = *(const bf16x8*)(&Bu[(wn * 32 + ni * 16 + lr) * 40 + lg * 8]);
      }
#pragma unroll
      for (int mi = 0; mi < 4; ++mi)
#pragma unroll
        for (int ni = 0; ni < 2; ++ni) {
          accg[mi][ni] = __builtin_amdgcn_mfma_f32_16x16x32_bf16(a[mi], bg[ni], accg[mi][ni], 0, 0, 0);
          accu[mi][ni] = __builtin_amdgcn_mfma_f32_16x16x32_bf16(a[mi], bu[ni], accu[mi][ni], 0, 0, 0);
        }
    }
    // epilogue: silu(g)*u -> bf16 act
#pragma unroll
    for (int mi = 0; mi < 4; ++mi)
#pragma unroll
      for (int ni = 0; ni < 2; ++ni)
#pragma unroll
        for (int r = 0; r < 4; ++r) {
          const int row = m0 + wm * 64 + mi * 16 + lg * 4 + r;
          const int col = nt * 128 + wn * 32 + ni * 16 + lr;
          const float g = accg[mi][ni][r], u = accu[mi][ni][r];
          const float v = (g / (1.f + __expf(-g))) * u;
          act[(size_t)(e * CAPE + row) * I_DIM + col] = f2bf(v);
        }
  }
}

// ---------------- K4: down GEMM -> y (bf16) --------------------------------
// grid = E * 16 (n-tiles of 128 over H=2048); block = 512 (8 waves, 2x4).
__global__ __launch_bounds__(512) void k_down(const unsigned short* __restrict__ act,
                                              const float* __restrict__ wd,
                                              const int* __restrict__ cnts,
                                              unsigned short* __restrict__ y) {
  const int e = blockIdx.x >> 4, nt = blockIdx.x & 15;
  int cnt = cnts[e]; cnt = cnt < CAPE ? cnt : CAPE;
  if (cnt <= 0) return;
  const int mtiles = (cnt + 127) >> 7;

  __shared__ __align__(16) short As[128 * 40];
  __shared__ __align__(16) short Bt[128 * 40];

  const int tid = threadIdx.x;
  const int lane = tid & 63, wave = tid >> 6;
  const int wm = wave >> 2, wn = wave & 3;
  const int lr = lane & 15, lg = lane >> 4;

  const int a_row = tid >> 2, a_ko = (tid & 3) * 8;        // 512 x 16B tasks
  const int b_kp = (tid & 7) | ((tid >> 8) << 3);
  const int b_nq = (tid >> 3) & 31;
  const int bk = 2 * b_kp, bn = 4 * b_nq;
  const size_t wbase = (size_t)e * I_DIM * H_DIM + (size_t)nt * 128;

  for (int mt = 0; mt < mtiles; ++mt) {
    const int m0 = mt << 7;
    f32x4 acc[4][2];
#pragma unroll
    for (int mi = 0; mi < 4; ++mi)
#pragma unroll
      for (int ni = 0; ni < 2; ++ni) acc[mi][ni] = (f32x4){0.f, 0.f, 0.f, 0.f};

    for (int kt = 0; kt < I_DIM / 32; ++kt) {
      const int k0 = kt * 32;
      __syncthreads();
      // A: bf16 copy from act
      *(bf16x8*)(&As[a_row * 40 + a_ko]) =
          *(const bf16x8*)(&act[(size_t)(e * CAPE + m0 + a_row) * I_DIM + k0 + a_ko]);
      // B: transpose-pack w_down
      {
        const size_t rb = wbase + (size_t)(k0 + bk) * H_DIM + bn;
        float4 d0 = *(const float4*)(wd + rb);
        float4 d1 = *(const float4*)(wd + rb + H_DIM);
        *(unsigned*)(&Bt[(bn + 0) * 40 + bk]) = pack2(d0.x, d1.x);
        *(unsigned*)(&Bt[(bn + 1) * 40 + bk]) = pack2(d0.y, d1.y);
        *(unsigned*)(&Bt[(bn + 2) * 40 + bk]) = pack2(d0.z, d1.z);
        *(unsigned*)(&Bt[(bn + 3) * 40 + bk]) = pack2(d0.w, d1.w);
      }
      __syncthreads();
      bf16x8 a[4], b[2];
#pragma unroll
      for (int mi = 0; mi < 4; ++mi)
        a[mi] = *(const bf16x8*)(&As[(wm * 64 + mi * 16 + lr) * 40 + lg * 8]);
#pragma unroll
      for (int ni = 0; ni < 2; ++ni)
        b[ni] = *(const bf16x8*)(&Bt[(wn * 32 + ni * 16 + lr) * 40 + lg * 8]);
#pragma unroll
      for (int mi = 0; mi < 4; ++mi)
#pragma unroll
        for (int ni = 0; ni < 2; ++ni)
          acc[mi][ni] = __builtin_amdgcn_mfma_f32_16x16x32_bf16(a[mi], b[ni], acc[mi][ni], 0, 0, 0);
    }
#pragma unroll
    for (int mi = 0; mi < 4; ++mi)
#pragma unroll
      for (int ni = 0; ni < 2; ++ni)
#pragma unroll
        for (int r = 0; r < 4; ++r) {
          const int row = m0 + wm * 64 + mi * 16 + lg * 4 + r;
          const int col = nt * 128 + wn * 32 + ni * 16 + lr;
          y[(size_t)(e * CAPE + row) * H_DIM + col] = f2bf(acc[mi][ni][r]);
        }
  }
}

// ---------------- K5: combine (deterministic gather) -----------------------
__global__ __launch_bounds__(256) void k_combine(const unsigned short* __restrict__ y,
                                                 const int* __restrict__ topk_idx,
                                                 const float* __restrict__ topk_w,
                                                 const int* __restrict__ pair_pos,
                                                 float* __restrict__ out) {
  const int t = blockIdx.x;
  __shared__ int s_e[TOPK]; __shared__ int s_p[TOPK]; __shared__ float s_w[TOPK];
  if (threadIdx.x < TOPK) {
    s_e[threadIdx.x] = topk_idx[t * TOPK + threadIdx.x];
    s_p[threadIdx.x] = pair_pos[t * TOPK + threadIdx.x];
    s_w[threadIdx.x] = topk_w [t * TOPK + threadIdx.x];
  }
  __syncthreads();
  const int h0 = threadIdx.x * 8;
  float acc[8] = {0.f, 0.f, 0.f, 0.f, 0.f, 0.f, 0.f, 0.f};
#pragma unroll
  for (int k = 0; k < TOPK; ++k) {
    const int pos = s_p[k];
    if (pos >= CAPE) continue;            // capacity-dropped pair
    const float w = s_w[k];
    const bf16x8 v = *(const bf16x8*)(&y[(size_t)(s_e[k] * CAPE + pos) * H_DIM + h0]);
#pragma unroll
    for (int j = 0; j < 8; ++j) acc[j] += w * bf2f((unsigned short)v[j]);
  }
  float4 o0 = {acc[0], acc[1], acc[2], acc[3]};
  float4 o1 = {acc[4], acc[5], acc[6], acc[7]};
  *(float4*)(out + (size_t)t * H_DIM + h0)     = o0;
  *(float4*)(out + (size_t)t * H_DIM + h0 + 4) = o1;
}

// ---------------------------------------------------------------------------
extern "C" void kernel_launch(void* const* d_in, const int* in_sizes, int n_in,
                              void* d_out, int out_size, void* d_ws, size_t ws_size,
                              hipStream_t stream) {
  const float* x   = (const float*)d_in[0];
  const float* wr  = (const float*)d_in[1];
  const float* wgt = (const float*)d_in[2];
  const float* wup = (const float*)d_in[3];
  const float* wdn = (const float*)d_in[4];
  float* out = (float*)d_out;

  char* ws = (char*)d_ws;
  int*            topk_idx   = (int*)(ws);                    //  64 KiB
  float*          topk_w     = (float*)(ws + 65536);          //  64 KiB
  int*            pair_pos   = (int*)(ws + 131072);           //  64 KiB
  int*            cnts       = (int*)(ws + 196608);           // 256 B
  int*            slot_token = (int*)(ws + 196864);           // 128 KiB
  unsigned short* act        = (unsigned short*)(ws + 327936);            // 48 MiB
  unsigned short* yb         = (unsigned short*)(ws + 327936 + 50331648); // 128 MiB

  k_router <<<dim3(T_TOK / 4), dim3(256), 0, stream>>>(x, wr, topk_idx, topk_w);
  k_rank   <<<dim3(1),         dim3(256), 0, stream>>>(topk_idx, pair_pos, slot_token, cnts);
  k_gateup <<<dim3(NEXP * 6),  dim3(512), 0, stream>>>(x, wgt, wup, slot_token, cnts, act);
  k_down   <<<dim3(NEXP * 16), dim3(512), 0, stream>>>(act, wdn, cnts, yb);
  k_combine<<<dim3(T_TOK),     dim3(256), 0, stream>>>(yb, topk_idx, topk_w, pair_pos, out);
}

// Round 2
// 909.076 us; speedup vs baseline: 1.1956x; 1.1956x over previous
//
#include <hip/hip_runtime.h>
#include <hip/hip_bf16.h>
#include <math.h>

// Problem constants (Qwen3 MoE block)
#define T_TOK 2048
#define H_DIM 2048
#define NEXP  64
#define TOPK  8
#define I_DIM 768
#define CAPE  512
#define MTMAX 4   // CAPE/128

typedef short bf16x8 __attribute__((ext_vector_type(8)));
typedef short bf16x4 __attribute__((ext_vector_type(4)));
typedef float f32x4  __attribute__((ext_vector_type(4)));

__device__ __forceinline__ unsigned short f2bf(float f) {
  unsigned u = __float_as_uint(f);
  u += 0x7fffu + ((u >> 16) & 1u);   // RNE
  return (unsigned short)(u >> 16);
}
__device__ __forceinline__ float bf2f(unsigned short b) {
  return __uint_as_float(((unsigned)b) << 16);
}
__device__ __forceinline__ unsigned pack2(float lo, float hi) {
  return (unsigned)f2bf(lo) | ((unsigned)f2bf(hi) << 16);
}

// ---------------- K1: router logits + softmax-top8 + renorm ----------------
__global__ __launch_bounds__(256) void k_router(const float* __restrict__ x,
                                                const float* __restrict__ wr,
                                                int* __restrict__ topk_idx,
                                                float* __restrict__ topk_w) {
  const int lane = threadIdx.x & 63;
  const int t = blockIdx.x * 4 + (threadIdx.x >> 6);
  const float4* xr   = (const float4*)(x + (size_t)t * H_DIM);
  const float4* wrow = (const float4*)(wr + (size_t)lane * H_DIM);
  double acc = 0.0;                      // fp64: minimize top-k tie risk
  for (int i = 0; i < H_DIM / 4; ++i) {
    float4 a = xr[i], b = wrow[i];
    acc += (double)a.x * b.x; acc += (double)a.y * b.y;
    acc += (double)a.z * b.z; acc += (double)a.w * b.w;
  }
  float cur = (float)acc;
  float val[TOPK]; int idx[TOPK];
#pragma unroll
  for (int r = 0; r < TOPK; ++r) {
    float bv = cur; int bi = lane;
#pragma unroll
    for (int off = 32; off > 0; off >>= 1) {   // argmax, ties -> lower index
      float ov = __shfl_xor(bv, off);
      int   oi = __shfl_xor(bi, off);
      if (ov > bv || (ov == bv && oi < bi)) { bv = ov; bi = oi; }
    }
    val[r] = bv; idx[r] = bi;
    if (lane == bi) cur = -INFINITY;
  }
  float m = val[0], s = 0.f, w[TOPK];
#pragma unroll
  for (int r = 0; r < TOPK; ++r) { w[r] = expf(val[r] - m); s += w[r]; }
  if (lane < TOPK) {
    topk_idx[t * TOPK + lane] = idx[lane];
    topk_w [t * TOPK + lane] = w[lane] / s;
  }
}

// ---------------- K2: stable rank within expert ----------------------------
__global__ __launch_bounds__(256) void k_rank(const int* __restrict__ topk_idx,
                                              int* __restrict__ pair_pos,
                                              int* __restrict__ slot_token,
                                              int* __restrict__ cnts) {
  __shared__ int s_run[64];
  __shared__ int s_whist[4][64];
  const int tid = threadIdx.x, lane = tid & 63, wv = tid >> 6;
  if (tid < 64) s_run[tid] = 0;
  for (int c = 0; c < 64; ++c) {
    const int p = c * 256 + tid;
    const int e = topk_idx[p];
    __syncthreads();
    s_whist[wv][lane] = 0;
    __syncthreads();
    unsigned long long m = ~0ull;
#pragma unroll
    for (int b = 0; b < 6; ++b) {
      unsigned long long bb = __ballot((e >> b) & 1);
      m &= ((e >> b) & 1) ? bb : ~bb;
    }
    const int rw = __popcll(m & ((1ull << lane) - 1ull));
    if (rw == 0) s_whist[wv][e] = __popcll(m);
    __syncthreads();
    int r = rw;
    for (int w2 = 0; w2 < wv; ++w2) r += s_whist[w2][e];
    const int pos = s_run[e] + r;
    pair_pos[p] = pos;
    if (pos < CAPE) slot_token[e * CAPE + pos] = p >> 3;
    __syncthreads();
    if (tid < 64)
      s_run[tid] += s_whist[0][tid] + s_whist[1][tid] + s_whist[2][tid] + s_whist[3][tid];
  }
  __syncthreads();
  if (tid < 64) cnts[tid] = s_run[tid];
}

// ---------------- K3: fused gate+up GEMM + SwiGLU -> act (bf16) ------------
// grid = E*MTMAX*6; block = 512 (8 waves, 2x4). 2-phase reg pipeline.
__global__ __launch_bounds__(512) void k_gateup(const float* __restrict__ x,
                                                const float* __restrict__ wg,
                                                const float* __restrict__ wu,
                                                const int* __restrict__ slot_token,
                                                const int* __restrict__ cnts,
                                                unsigned short* __restrict__ act) {
  // XCD-chunk swizzle: each XCD owns a contiguous range of virtual ids
  const int NB = NEXP * MTMAX * 6;
  const int v = (blockIdx.x & 7) * (NB / 8) + (blockIdx.x >> 3);
  const int e = v / (MTMAX * 6);
  const int rem = v % (MTMAX * 6);
  const int mt = rem / 6, nt = rem % 6;

  int cnt = cnts[e]; cnt = cnt < CAPE ? cnt : CAPE;
  if (cnt <= 0 || mt * 128 >= cnt) return;
  const int m0 = mt << 7;

  __shared__ __align__(16) short As[128 * 40];
  __shared__ __align__(16) short Bg[128 * 40];
  __shared__ __align__(16) short Bu[128 * 40];

  const int tid = threadIdx.x;
  const int lane = tid & 63, wave = tid >> 6;
  const int wm = wave >> 2, wn = wave & 3;       // 2x4 wave grid, 64x32 tiles
  const int lr = lane & 15, lg = lane >> 4;

  // A staging: rows tid>>3 and +64, col-quad tid&7
  const int a_row0 = tid >> 3, a_kq = tid & 7;
  const int a_row1 = a_row0 + 64;
  // B staging: kp = tid&15 (k-pair), nq = tid>>4 (n-quad)
  const int b_kp = tid & 15, b_nq = tid >> 4;
  const int bk = 2 * b_kp, bn = 4 * b_nq;
  const size_t wbase = (size_t)e * H_DIM * I_DIM + (size_t)nt * 128;

  const int tok0 = (m0 + a_row0 < cnt) ? slot_token[e * CAPE + m0 + a_row0] : 0;
  const int tok1 = (m0 + a_row1 < cnt) ? slot_token[e * CAPE + m0 + a_row1] : 0;
  const float* xr0 = x + (size_t)tok0 * H_DIM + a_kq * 4;
  const float* xr1 = x + (size_t)tok1 * H_DIM + a_kq * 4;
  const float* gp  = wg + wbase + (size_t)bk * I_DIM + bn;
  const float* up  = wu + wbase + (size_t)bk * I_DIM + bn;

  f32x4 accg[4][2], accu[4][2];
#pragma unroll
  for (int mi = 0; mi < 4; ++mi)
#pragma unroll
    for (int ni = 0; ni < 2; ++ni) {
      accg[mi][ni] = (f32x4){0.f, 0.f, 0.f, 0.f};
      accu[mi][ni] = (f32x4){0.f, 0.f, 0.f, 0.f};
    }

  // prologue: load tile 0 into regs
  float4 va0 = *(const float4*)(xr0);
  float4 va1 = *(const float4*)(xr1);
  float4 g0  = *(const float4*)(gp);
  float4 g1  = *(const float4*)(gp + I_DIM);
  float4 u0  = *(const float4*)(up);
  float4 u1  = *(const float4*)(up + I_DIM);

  const int NK = H_DIM / 32;
  for (int kt = 0; kt < NK; ++kt) {
    if (kt) __syncthreads();               // all frag reads of LDS done
    { // write regs -> LDS
      bf16x4 s0, s1;
      s0[0]=(short)f2bf(va0.x); s0[1]=(short)f2bf(va0.y); s0[2]=(short)f2bf(va0.z); s0[3]=(short)f2bf(va0.w);
      s1[0]=(short)f2bf(va1.x); s1[1]=(short)f2bf(va1.y); s1[2]=(short)f2bf(va1.z); s1[3]=(short)f2bf(va1.w);
      *(bf16x4*)(&As[a_row0 * 40 + a_kq * 4]) = s0;
      *(bf16x4*)(&As[a_row1 * 40 + a_kq * 4]) = s1;
      *(unsigned*)(&Bg[(bn + 0) * 40 + bk]) = pack2(g0.x, g1.x);
      *(unsigned*)(&Bg[(bn + 1) * 40 + bk]) = pack2(g0.y, g1.y);
      *(unsigned*)(&Bg[(bn + 2) * 40 + bk]) = pack2(g0.z, g1.z);
      *(unsigned*)(&Bg[(bn + 3) * 40 + bk]) = pack2(g0.w, g1.w);
      *(unsigned*)(&Bu[(bn + 0) * 40 + bk]) = pack2(u0.x, u1.x);
      *(unsigned*)(&Bu[(bn + 1) * 40 + bk]) = pack2(u0.y, u1.y);
      *(unsigned*)(&Bu[(bn + 2) * 40 + bk]) = pack2(u0.z, u1.z);
      *(unsigned*)(&Bu[(bn + 3) * 40 + bk]) = pack2(u0.w, u1.w);
    }
    __syncthreads();
    if (kt + 1 < NK) {                     // issue next-tile loads early
      const int k1 = (kt + 1) * 32;
      va0 = *(const float4*)(xr0 + k1);
      va1 = *(const float4*)(xr1 + k1);
      g0  = *(const float4*)(gp + (size_t)k1 * I_DIM);
      g1  = *(const float4*)(gp + (size_t)(k1 + 1) * I_DIM - I_DIM + I_DIM);  // == gp+(k1)*I+I
      g1  = *(const float4*)(gp + (size_t)k1 * I_DIM + I_DIM);
      u0  = *(const float4*)(up + (size_t)k1 * I_DIM);
      u1  = *(const float4*)(up + (size_t)k1 * I_DIM + I_DIM);
    }
    bf16x8 a[4], bg[2], bu[2];
#pragma unroll
    for (int mi = 0; mi < 4; ++mi)
      a[mi] = *(const bf16x8*)(&As[(wm * 64 + mi * 16 + lr) * 40 + lg * 8]);
#pragma unroll
    for (int ni = 0; ni < 2; ++ni) {
      bg[ni] = *(const bf16x8*)(&Bg[(wn * 32 + ni * 16 + lr) * 40 + lg * 8]);
      bu[ni] = *(const bf16x8*)(&Bu[(wn * 32 + ni * 16 + lr) * 40 + lg * 8]);
    }
#pragma unroll
    for (int mi = 0; mi < 4; ++mi)
#pragma unroll
      for (int ni = 0; ni < 2; ++ni) {
        accg[mi][ni] = __builtin_amdgcn_mfma_f32_16x16x32_bf16(a[mi], bg[ni], accg[mi][ni], 0, 0, 0);
        accu[mi][ni] = __builtin_amdgcn_mfma_f32_16x16x32_bf16(a[mi], bu[ni], accu[mi][ni], 0, 0, 0);
      }
  }
  // epilogue: silu(g)*u -> bf16 act
#pragma unroll
  for (int mi = 0; mi < 4; ++mi)
#pragma unroll
    for (int ni = 0; ni < 2; ++ni)
#pragma unroll
      for (int r = 0; r < 4; ++r) {
        const int row = m0 + wm * 64 + mi * 16 + lg * 4 + r;
        const int col = nt * 128 + wn * 32 + ni * 16 + lr;
        const float g = accg[mi][ni][r], u = accu[mi][ni][r];
        const float v = (g / (1.f + __expf(-g))) * u;
        act[(size_t)(e * CAPE + row) * I_DIM + col] = f2bf(v);
      }
}

// ---------------- K4: down GEMM -> y (bf16) --------------------------------
// grid = E*MTMAX*16; block = 512 (8 waves, 2x4). 2-phase reg pipeline.
__global__ __launch_bounds__(512) void k_down(const unsigned short* __restrict__ act,
                                              const float* __restrict__ wd,
                                              const int* __restrict__ cnts,
                                              unsigned short* __restrict__ y) {
  const int NB = NEXP * MTMAX * 16;
  const int v = (blockIdx.x & 7) * (NB / 8) + (blockIdx.x >> 3);
  const int e = v / (MTMAX * 16);
  const int rem = v % (MTMAX * 16);
  const int mt = rem / 16, nt = rem % 16;

  int cnt = cnts[e]; cnt = cnt < CAPE ? cnt : CAPE;
  if (cnt <= 0 || mt * 128 >= cnt) return;
  const int m0 = mt << 7;

  __shared__ __align__(16) short As[128 * 40];
  __shared__ __align__(16) short Bt[128 * 40];

  const int tid = threadIdx.x;
  const int lane = tid & 63, wave = tid >> 6;
  const int wm = wave >> 2, wn = wave & 3;
  const int lr = lane & 15, lg = lane >> 4;

  const int a_row = tid >> 2, a_ko = (tid & 3) * 8;   // 512 x 16B tasks
  const int b_kp = tid & 15, b_nq = tid >> 4;
  const int bk = 2 * b_kp, bn = 4 * b_nq;
  const size_t wbase = (size_t)e * I_DIM * H_DIM + (size_t)nt * 128;

  const unsigned short* ap = act + (size_t)(e * CAPE + m0 + a_row) * I_DIM + a_ko;
  const float* dp = wd + wbase + (size_t)bk * H_DIM + bn;

  f32x4 acc[4][2];
#pragma unroll
  for (int mi = 0; mi < 4; ++mi)
#pragma unroll
    for (int ni = 0; ni < 2; ++ni) acc[mi][ni] = (f32x4){0.f, 0.f, 0.f, 0.f};

  // prologue
  bf16x8 ra = *(const bf16x8*)(ap);
  float4 d0 = *(const float4*)(dp);
  float4 d1 = *(const float4*)(dp + H_DIM);

  const int NK = I_DIM / 32;
  for (int kt = 0; kt < NK; ++kt) {
    if (kt) __syncthreads();
    *(bf16x8*)(&As[a_row * 40 + a_ko]) = ra;
    *(unsigned*)(&Bt[(bn + 0) * 40 + bk]) = pack2(d0.x, d1.x);
    *(unsigned*)(&Bt[(bn + 1) * 40 + bk]) = pack2(d0.y, d1.y);
    *(unsigned*)(&Bt[(bn + 2) * 40 + bk]) = pack2(d0.z, d1.z);
    *(unsigned*)(&Bt[(bn + 3) * 40 + bk]) = pack2(d0.w, d1.w);
    __syncthreads();
    if (kt + 1 < NK) {
      const int k1 = (kt + 1) * 32;
      ra = *(const bf16x8*)(ap + k1);
      d0 = *(const float4*)(dp + (size_t)k1 * H_DIM);
      d1 = *(const float4*)(dp + (size_t)k1 * H_DIM + H_DIM);
    }
    bf16x8 a[4], b[2];
#pragma unroll
    for (int mi = 0; mi < 4; ++mi)
      a[mi] = *(const bf16x8*)(&As[(wm * 64 + mi * 16 + lr) * 40 + lg * 8]);
#pragma unroll
    for (int ni = 0; ni < 2; ++ni)
      b[ni] = *(const bf16x8*)(&Bt[(wn * 32 + ni * 16 + lr) * 40 + lg * 8]);
#pragma unroll
    for (int mi = 0; mi < 4; ++mi)
#pragma unroll
      for (int ni = 0; ni < 2; ++ni)
        acc[mi][ni] = __builtin_amdgcn_mfma_f32_16x16x32_bf16(a[mi], b[ni], acc[mi][ni], 0, 0, 0);
  }
#pragma unroll
  for (int mi = 0; mi < 4; ++mi)
#pragma unroll
    for (int ni = 0; ni < 2; ++ni)
#pragma unroll
      for (int r = 0; r < 4; ++r) {
        const int row = m0 + wm * 64 + mi * 16 + lg * 4 + r;
        const int col = nt * 128 + wn * 32 + ni * 16 + lr;
        y[(size_t)(e * CAPE + row) * H_DIM + col] = f2bf(acc[mi][ni][r]);
      }
}

// ---------------- K5: combine (deterministic gather) -----------------------
__global__ __launch_bounds__(256) void k_combine(const unsigned short* __restrict__ y,
                                                 const int* __restrict__ topk_idx,
                                                 const float* __restrict__ topk_w,
                                                 const int* __restrict__ pair_pos,
                                                 float* __restrict__ out) {
  const int t = blockIdx.x;
  __shared__ int s_e[TOPK]; __shared__ int s_p[TOPK]; __shared__ float s_w[TOPK];
  if (threadIdx.x < TOPK) {
    s_e[threadIdx.x] = topk_idx[t * TOPK + threadIdx.x];
    s_p[threadIdx.x] = pair_pos[t * TOPK + threadIdx.x];
    s_w[threadIdx.x] = topk_w [t * TOPK + threadIdx.x];
  }
  __syncthreads();
  const int h0 = threadIdx.x * 8;
  float acc[8] = {0.f, 0.f, 0.f, 0.f, 0.f, 0.f, 0.f, 0.f};
#pragma unroll
  for (int k = 0; k < TOPK; ++k) {
    const int pos = s_p[k];
    if (pos >= CAPE) continue;
    const float w = s_w[k];
    const bf16x8 v = *(const bf16x8*)(&y[(size_t)(s_e[k] * CAPE + pos) * H_DIM + h0]);
#pragma unroll
    for (int j = 0; j < 8; ++j) acc[j] += w * bf2f((unsigned short)v[j]);
  }
  float4 o0 = {acc[0], acc[1], acc[2], acc[3]};
  float4 o1 = {acc[4], acc[5], acc[6], acc[7]};
  *(float4*)(out + (size_t)t * H_DIM + h0)     = o0;
  *(float4*)(out + (size_t)t * H_DIM + h0 + 4) = o1;
}

// ---------------------------------------------------------------------------
extern "C" void kernel_launch(void* const* d_in, const int* in_sizes, int n_in,
                              void* d_out, int out_size, void* d_ws, size_t ws_size,
                              hipStream_t stream) {
  const float* x   = (const float*)d_in[0];
  const float* wr  = (const float*)d_in[1];
  const float* wgt = (const float*)d_in[2];
  const float* wup = (const float*)d_in[3];
  const float* wdn = (const float*)d_in[4];
  float* out = (float*)d_out;

  char* ws = (char*)d_ws;
  int*            topk_idx   = (int*)(ws);                    //  64 KiB
  float*          topk_w     = (float*)(ws + 65536);          //  64 KiB
  int*            pair_pos   = (int*)(ws + 131072);           //  64 KiB
  int*            cnts       = (int*)(ws + 196608);           // 256 B
  int*            slot_token = (int*)(ws + 196864);           // 128 KiB
  unsigned short* act        = (unsigned short*)(ws + 327936);            // 48 MiB
  unsigned short* yb         = (unsigned short*)(ws + 327936 + 50331648); // 128 MiB

  k_router <<<dim3(T_TOK / 4),        dim3(256), 0, stream>>>(x, wr, topk_idx, topk_w);
  k_rank   <<<dim3(1),                dim3(256), 0, stream>>>(topk_idx, pair_pos, slot_token, cnts);
  k_gateup <<<dim3(NEXP * MTMAX * 6), dim3(512), 0, stream>>>(x, wgt, wup, slot_token, cnts, act);
  k_down   <<<dim3(NEXP * MTMAX * 16),dim3(512), 0, stream>>>(act, wdn, cnts, yb);
  k_combine<<<dim3(T_TOK),            dim3(256), 0, stream>>>(yb, topk_idx, topk_w, pair_pos, out);
}

// Round 3
// 803.603 us; speedup vs baseline: 1.3526x; 1.1313x over previous
//
#include <hip/hip_runtime.h>
#include <hip/hip_bf16.h>
#include <math.h>

// Problem constants (Qwen3 MoE block)
#define T_TOK 2048
#define H_DIM 2048
#define NEXP  64
#define TOPK  8
#define I_DIM 768
#define CAPE  512
#define MTMAX 4   // CAPE/128
#define LDW   40  // LDS row stride in shorts (80B: 16B-aligned, 2-way-free banks)

typedef short bf16x8 __attribute__((ext_vector_type(8)));
typedef short bf16x4 __attribute__((ext_vector_type(4)));
typedef float f32x4  __attribute__((ext_vector_type(4)));

__device__ __forceinline__ unsigned short f2bf(float f) {
  unsigned u = __float_as_uint(f);
  u += 0x7fffu + ((u >> 16) & 1u);   // RNE
  return (unsigned short)(u >> 16);
}
__device__ __forceinline__ float bf2f(unsigned short b) {
  return __uint_as_float(((unsigned)b) << 16);
}
__device__ __forceinline__ unsigned pack2(float lo, float hi) {
  return (unsigned)f2bf(lo) | ((unsigned)f2bf(hi) << 16);
}

// ---------------- K1: router logits + softmax-top8 + renorm ----------------
__global__ __launch_bounds__(256) void k_router(const float* __restrict__ x,
                                                const float* __restrict__ wr,
                                                int* __restrict__ topk_idx,
                                                float* __restrict__ topk_w) {
  const int lane = threadIdx.x & 63;
  const int t = blockIdx.x * 4 + (threadIdx.x >> 6);
  const float4* xr   = (const float4*)(x + (size_t)t * H_DIM);
  const float4* wrow = (const float4*)(wr + (size_t)lane * H_DIM);
  double acc = 0.0;                      // fp64: minimize top-k tie risk
  for (int i = 0; i < H_DIM / 4; ++i) {
    float4 a = xr[i], b = wrow[i];
    acc += (double)a.x * b.x; acc += (double)a.y * b.y;
    acc += (double)a.z * b.z; acc += (double)a.w * b.w;
  }
  float cur = (float)acc;
  float val[TOPK]; int idx[TOPK];
#pragma unroll
  for (int r = 0; r < TOPK; ++r) {
    float bv = cur; int bi = lane;
#pragma unroll
    for (int off = 32; off > 0; off >>= 1) {   // argmax, ties -> lower index
      float ov = __shfl_xor(bv, off);
      int   oi = __shfl_xor(bi, off);
      if (ov > bv || (ov == bv && oi < bi)) { bv = ov; bi = oi; }
    }
    val[r] = bv; idx[r] = bi;
    if (lane == bi) cur = -INFINITY;
  }
  float m = val[0], s = 0.f, w[TOPK];
#pragma unroll
  for (int r = 0; r < TOPK; ++r) { w[r] = expf(val[r] - m); s += w[r]; }
  if (lane < TOPK) {
    topk_idx[t * TOPK + lane] = idx[lane];
    topk_w [t * TOPK + lane] = w[lane] / s;
  }
}

// ---------------- K2: stable rank within expert ----------------------------
__global__ __launch_bounds__(256) void k_rank(const int* __restrict__ topk_idx,
                                              int* __restrict__ pair_pos,
                                              int* __restrict__ slot_token,
                                              int* __restrict__ cnts) {
  __shared__ int s_run[64];
  __shared__ int s_whist[4][64];
  const int tid = threadIdx.x, lane = tid & 63, wv = tid >> 6;
  if (tid < 64) s_run[tid] = 0;
  for (int c = 0; c < 64; ++c) {
    const int p = c * 256 + tid;
    const int e = topk_idx[p];
    __syncthreads();
    s_whist[wv][lane] = 0;
    __syncthreads();
    unsigned long long m = ~0ull;
#pragma unroll
    for (int b = 0; b < 6; ++b) {
      unsigned long long bb = __ballot((e >> b) & 1);
      m &= ((e >> b) & 1) ? bb : ~bb;
    }
    const int rw = __popcll(m & ((1ull << lane) - 1ull));
    if (rw == 0) s_whist[wv][e] = __popcll(m);
    __syncthreads();
    int r = rw;
    for (int w2 = 0; w2 < wv; ++w2) r += s_whist[w2][e];
    const int pos = s_run[e] + r;
    pair_pos[p] = pos;
    if (pos < CAPE) slot_token[e * CAPE + pos] = p >> 3;
    __syncthreads();
    if (tid < 64)
      s_run[tid] += s_whist[0][tid] + s_whist[1][tid] + s_whist[2][tid] + s_whist[3][tid];
  }
  __syncthreads();
  if (tid < 64) cnts[tid] = s_run[tid];
}

// ---------------- K3: fused gate+up GEMM + SwiGLU -> act (bf16) ------------
// grid = E*MTMAX*6; block = 512 (8 waves, 2x4). LDS dbuf + 2-deep reg rotation,
// ONE barrier per k-step.
__global__ __launch_bounds__(512) void k_gateup(const float* __restrict__ x,
                                                const float* __restrict__ wg,
                                                const float* __restrict__ wu,
                                                const int* __restrict__ slot_token,
                                                const int* __restrict__ cnts,
                                                unsigned short* __restrict__ act) {
  const int NB = NEXP * MTMAX * 6;
  const int v = (blockIdx.x & 7) * (NB / 8) + (blockIdx.x >> 3);  // XCD chunk swizzle
  const int e = v / (MTMAX * 6);
  const int rem = v % (MTMAX * 6);
  const int mt = rem / 6, nt = rem % 6;

  int cnt = cnts[e]; cnt = cnt < CAPE ? cnt : CAPE;
  if (cnt <= 0 || mt * 128 >= cnt) return;
  const int m0 = mt << 7;

  __shared__ __align__(16) short As[2][128 * LDW];   // 20 KiB
  __shared__ __align__(16) short Bg[2][128 * LDW];   // 20 KiB
  __shared__ __align__(16) short Bu[2][128 * LDW];   // 20 KiB

  const int tid = threadIdx.x;
  const int lane = tid & 63, wave = tid >> 6;
  const int wm = wave >> 2, wn = wave & 3;       // 2x4 wave grid, 64x32 tiles
  const int lr = lane & 15, lg = lane >> 4;

  // A staging: rows tid>>3 and +64, col-quad tid&7
  const int a_row0 = tid >> 3, a_kq = tid & 7;
  const int a_row1 = a_row0 + 64;
  // B staging: kp = tid&15 (k-pair), nq = tid>>4 (n-quad); banks 2-way-free
  const int b_kp = tid & 15, b_nq = tid >> 4;
  const int bk = 2 * b_kp, bn = 4 * b_nq;
  const size_t wbase = (size_t)e * H_DIM * I_DIM + (size_t)nt * 128;

  const int tok0 = (m0 + a_row0 < cnt) ? slot_token[e * CAPE + m0 + a_row0] : 0;
  const int tok1 = (m0 + a_row1 < cnt) ? slot_token[e * CAPE + m0 + a_row1] : 0;
  const float* xr0 = x + (size_t)tok0 * H_DIM + a_kq * 4;
  const float* xr1 = x + (size_t)tok1 * H_DIM + a_kq * 4;
  const float* gp  = wg + wbase + (size_t)bk * I_DIM + bn;
  const float* up  = wu + wbase + (size_t)bk * I_DIM + bn;

  f32x4 accg[4][2], accu[4][2];
#pragma unroll
  for (int mi = 0; mi < 4; ++mi)
#pragma unroll
    for (int ni = 0; ni < 2; ++ni) {
      accg[mi][ni] = (f32x4){0.f, 0.f, 0.f, 0.f};
      accu[mi][ni] = (f32x4){0.f, 0.f, 0.f, 0.f};
    }

  struct Tile { float4 a0, a1, g0, g1, u0, u1; };

  auto LOAD = [&](Tile& Tl, int kt) {
    const int k0 = kt * 32;
    Tl.a0 = *(const float4*)(xr0 + k0);
    Tl.a1 = *(const float4*)(xr1 + k0);
    Tl.g0 = *(const float4*)(gp + (size_t)k0 * I_DIM);
    Tl.g1 = *(const float4*)(gp + (size_t)k0 * I_DIM + I_DIM);
    Tl.u0 = *(const float4*)(up + (size_t)k0 * I_DIM);
    Tl.u1 = *(const float4*)(up + (size_t)k0 * I_DIM + I_DIM);
  };
  auto STORE = [&](const Tile& Tl, int b) {
    bf16x4 s0, s1;
    s0[0]=(short)f2bf(Tl.a0.x); s0[1]=(short)f2bf(Tl.a0.y); s0[2]=(short)f2bf(Tl.a0.z); s0[3]=(short)f2bf(Tl.a0.w);
    s1[0]=(short)f2bf(Tl.a1.x); s1[1]=(short)f2bf(Tl.a1.y); s1[2]=(short)f2bf(Tl.a1.z); s1[3]=(short)f2bf(Tl.a1.w);
    *(bf16x4*)(&As[b][a_row0 * LDW + a_kq * 4]) = s0;
    *(bf16x4*)(&As[b][a_row1 * LDW + a_kq * 4]) = s1;
    *(unsigned*)(&Bg[b][(bn + 0) * LDW + bk]) = pack2(Tl.g0.x, Tl.g1.x);
    *(unsigned*)(&Bg[b][(bn + 1) * LDW + bk]) = pack2(Tl.g0.y, Tl.g1.y);
    *(unsigned*)(&Bg[b][(bn + 2) * LDW + bk]) = pack2(Tl.g0.z, Tl.g1.z);
    *(unsigned*)(&Bg[b][(bn + 3) * LDW + bk]) = pack2(Tl.g0.w, Tl.g1.w);
    *(unsigned*)(&Bu[b][(bn + 0) * LDW + bk]) = pack2(Tl.u0.x, Tl.u1.x);
    *(unsigned*)(&Bu[b][(bn + 1) * LDW + bk]) = pack2(Tl.u0.y, Tl.u1.y);
    *(unsigned*)(&Bu[b][(bn + 2) * LDW + bk]) = pack2(Tl.u0.z, Tl.u1.z);
    *(unsigned*)(&Bu[b][(bn + 3) * LDW + bk]) = pack2(Tl.u0.w, Tl.u1.w);
  };
  auto COMPUTE = [&](int b) {
    bf16x8 a[4], bg[2], bu[2];
#pragma unroll
    for (int mi = 0; mi < 4; ++mi)
      a[mi] = *(const bf16x8*)(&As[b][(wm * 64 + mi * 16 + lr) * LDW + lg * 8]);
#pragma unroll
    for (int ni = 0; ni < 2; ++ni) {
      bg[ni] = *(const bf16x8*)(&Bg[b][(wn * 32 + ni * 16 + lr) * LDW + lg * 8]);
      bu[ni] = *(const bf16x8*)(&Bu[b][(wn * 32 + ni * 16 + lr) * LDW + lg * 8]);
    }
#pragma unroll
    for (int mi = 0; mi < 4; ++mi)
#pragma unroll
      for (int ni = 0; ni < 2; ++ni) {
        accg[mi][ni] = __builtin_amdgcn_mfma_f32_16x16x32_bf16(a[mi], bg[ni], accg[mi][ni], 0, 0, 0);
        accu[mi][ni] = __builtin_amdgcn_mfma_f32_16x16x32_bf16(a[mi], bu[ni], accu[mi][ni], 0, 0, 0);
      }
  };

  const int NK = H_DIM / 32;   // 64, even
  Tile tA, tB;
  LOAD(tA, 0);
  STORE(tA, 0);                 // waits only tA's loads
  LOAD(tB, 1);
  __syncthreads();

  int t = 0;
#pragma unroll 1
  for (; t + 2 < NK; t += 2) {
    LOAD(tA, t + 2);            // issue early: consumed at end of this iter
    COMPUTE(0);                 // tile t
    STORE(tB, 1);               // tile t+1 -> buf1 (loads had ~1 full step)
    __syncthreads();
    LOAD(tB, t + 3);
    COMPUTE(1);                 // tile t+1
    STORE(tA, 0);               // tile t+2 -> buf0
    __syncthreads();
  }
  COMPUTE(0);                   // tile NK-2
  STORE(tB, 1);                 // tile NK-1
  __syncthreads();
  COMPUTE(1);                   // tile NK-1

  // epilogue: silu(g)*u -> bf16 act
#pragma unroll
  for (int mi = 0; mi < 4; ++mi)
#pragma unroll
    for (int ni = 0; ni < 2; ++ni)
#pragma unroll
      for (int r = 0; r < 4; ++r) {
        const int row = m0 + wm * 64 + mi * 16 + lg * 4 + r;
        const int col = nt * 128 + wn * 32 + ni * 16 + lr;
        const float g = accg[mi][ni][r], u = accu[mi][ni][r];
        const float vv = (g / (1.f + __expf(-g))) * u;
        act[(size_t)(e * CAPE + row) * I_DIM + col] = f2bf(vv);
      }
}

// ---------------- K4: down GEMM -> y (bf16) --------------------------------
// grid = E*MTMAX*16; block = 512 (8 waves, 2x4). Same dbuf pipeline.
__global__ __launch_bounds__(512) void k_down(const unsigned short* __restrict__ act,
                                              const float* __restrict__ wd,
                                              const int* __restrict__ cnts,
                                              unsigned short* __restrict__ y) {
  const int NB = NEXP * MTMAX * 16;
  const int v = (blockIdx.x & 7) * (NB / 8) + (blockIdx.x >> 3);
  const int e = v / (MTMAX * 16);
  const int rem = v % (MTMAX * 16);
  const int mt = rem / 16, nt = rem % 16;

  int cnt = cnts[e]; cnt = cnt < CAPE ? cnt : CAPE;
  if (cnt <= 0 || mt * 128 >= cnt) return;
  const int m0 = mt << 7;

  __shared__ __align__(16) short As[2][128 * LDW];
  __shared__ __align__(16) short Bt[2][128 * LDW];

  const int tid = threadIdx.x;
  const int lane = tid & 63, wave = tid >> 6;
  const int wm = wave >> 2, wn = wave & 3;
  const int lr = lane & 15, lg = lane >> 4;

  const int a_row = tid >> 2, a_ko = (tid & 3) * 8;   // 512 x 16B tasks
  const int b_kp = tid & 15, b_nq = tid >> 4;
  const int bk = 2 * b_kp, bn = 4 * b_nq;
  const size_t wbase = (size_t)e * I_DIM * H_DIM + (size_t)nt * 128;

  const unsigned short* ap = act + (size_t)(e * CAPE + m0 + a_row) * I_DIM + a_ko;
  const float* dp = wd + wbase + (size_t)bk * H_DIM + bn;

  f32x4 acc[4][2];
#pragma unroll
  for (int mi = 0; mi < 4; ++mi)
#pragma unroll
    for (int ni = 0; ni < 2; ++ni) acc[mi][ni] = (f32x4){0.f, 0.f, 0.f, 0.f};

  struct Tile { bf16x8 a; float4 d0, d1; };

  auto LOAD = [&](Tile& Tl, int kt) {
    const int k0 = kt * 32;
    Tl.a  = *(const bf16x8*)(ap + k0);
    Tl.d0 = *(const float4*)(dp + (size_t)k0 * H_DIM);
    Tl.d1 = *(const float4*)(dp + (size_t)k0 * H_DIM + H_DIM);
  };
  auto STORE = [&](const Tile& Tl, int b) {
    *(bf16x8*)(&As[b][a_row * LDW + a_ko]) = Tl.a;
    *(unsigned*)(&Bt[b][(bn + 0) * LDW + bk]) = pack2(Tl.d0.x, Tl.d1.x);
    *(unsigned*)(&Bt[b][(bn + 1) * LDW + bk]) = pack2(Tl.d0.y, Tl.d1.y);
    *(unsigned*)(&Bt[b][(bn + 2) * LDW + bk]) = pack2(Tl.d0.z, Tl.d1.z);
    *(unsigned*)(&Bt[b][(bn + 3) * LDW + bk]) = pack2(Tl.d0.w, Tl.d1.w);
  };
  auto COMPUTE = [&](int b) {
    bf16x8 a[4], bb[2];
#pragma unroll
    for (int mi = 0; mi < 4; ++mi)
      a[mi] = *(const bf16x8*)(&As[b][(wm * 64 + mi * 16 + lr) * LDW + lg * 8]);
#pragma unroll
    for (int ni = 0; ni < 2; ++ni)
      bb[ni] = *(const bf16x8*)(&Bt[b][(wn * 32 + ni * 16 + lr) * LDW + lg * 8]);
#pragma unroll
    for (int mi = 0; mi < 4; ++mi)
#pragma unroll
      for (int ni = 0; ni < 2; ++ni)
        acc[mi][ni] = __builtin_amdgcn_mfma_f32_16x16x32_bf16(a[mi], bb[ni], acc[mi][ni], 0, 0, 0);
  };

  const int NK = I_DIM / 32;   // 24, even
  Tile tA, tB;
  LOAD(tA, 0);
  STORE(tA, 0);
  LOAD(tB, 1);
  __syncthreads();

  int t = 0;
#pragma unroll 1
  for (; t + 2 < NK; t += 2) {
    LOAD(tA, t + 2);
    COMPUTE(0);
    STORE(tB, 1);
    __syncthreads();
    LOAD(tB, t + 3);
    COMPUTE(1);
    STORE(tA, 0);
    __syncthreads();
  }
  COMPUTE(0);
  STORE(tB, 1);
  __syncthreads();
  COMPUTE(1);

#pragma unroll
  for (int mi = 0; mi < 4; ++mi)
#pragma unroll
    for (int ni = 0; ni < 2; ++ni)
#pragma unroll
      for (int r = 0; r < 4; ++r) {
        const int row = m0 + wm * 64 + mi * 16 + lg * 4 + r;
        const int col = nt * 128 + wn * 32 + ni * 16 + lr;
        y[(size_t)(e * CAPE + row) * H_DIM + col] = f2bf(acc[mi][ni][r]);
      }
}

// ---------------- K5: combine (deterministic gather) -----------------------
__global__ __launch_bounds__(256) void k_combine(const unsigned short* __restrict__ y,
                                                 const int* __restrict__ topk_idx,
                                                 const float* __restrict__ topk_w,
                                                 const int* __restrict__ pair_pos,
                                                 float* __restrict__ out) {
  const int t = blockIdx.x;
  __shared__ int s_e[TOPK]; __shared__ int s_p[TOPK]; __shared__ float s_w[TOPK];
  if (threadIdx.x < TOPK) {
    s_e[threadIdx.x] = topk_idx[t * TOPK + threadIdx.x];
    s_p[threadIdx.x] = pair_pos[t * TOPK + threadIdx.x];
    s_w[threadIdx.x] = topk_w [t * TOPK + threadIdx.x];
  }
  __syncthreads();
  const int h0 = threadIdx.x * 8;
  float acc[8] = {0.f, 0.f, 0.f, 0.f, 0.f, 0.f, 0.f, 0.f};
#pragma unroll
  for (int k = 0; k < TOPK; ++k) {
    const int pos = s_p[k];
    if (pos >= CAPE) continue;
    const float w = s_w[k];
    const bf16x8 vv = *(const bf16x8*)(&y[(size_t)(s_e[k] * CAPE + pos) * H_DIM + h0]);
#pragma unroll
    for (int j = 0; j < 8; ++j) acc[j] += w * bf2f((unsigned short)vv[j]);
  }
  float4 o0 = {acc[0], acc[1], acc[2], acc[3]};
  float4 o1 = {acc[4], acc[5], acc[6], acc[7]};
  *(float4*)(out + (size_t)t * H_DIM + h0)     = o0;
  *(float4*)(out + (size_t)t * H_DIM + h0 + 4) = o1;
}

// ---------------------------------------------------------------------------
extern "C" void kernel_launch(void* const* d_in, const int* in_sizes, int n_in,
                              void* d_out, int out_size, void* d_ws, size_t ws_size,
                              hipStream_t stream) {
  const float* x   = (const float*)d_in[0];
  const float* wr  = (const float*)d_in[1];
  const float* wgt = (const float*)d_in[2];
  const float* wup = (const float*)d_in[3];
  const float* wdn = (const float*)d_in[4];
  float* out = (float*)d_out;

  char* ws = (char*)d_ws;
  int*            topk_idx   = (int*)(ws);                    //  64 KiB
  float*          topk_w     = (float*)(ws + 65536);          //  64 KiB
  int*            pair_pos   = (int*)(ws + 131072);           //  64 KiB
  int*            cnts       = (int*)(ws + 196608);           // 256 B
  int*            slot_token = (int*)(ws + 196864);           // 128 KiB
  unsigned short* act        = (unsigned short*)(ws + 327936);            // 48 MiB
  unsigned short* yb         = (unsigned short*)(ws + 327936 + 50331648); // 128 MiB

  k_router <<<dim3(T_TOK / 4),        dim3(256), 0, stream>>>(x, wr, topk_idx, topk_w);
  k_rank   <<<dim3(1),                dim3(256), 0, stream>>>(topk_idx, pair_pos, slot_token, cnts);
  k_gateup <<<dim3(NEXP * MTMAX * 6), dim3(512), 0, stream>>>(x, wgt, wup, slot_token, cnts, act);
  k_down   <<<dim3(NEXP * MTMAX * 16),dim3(512), 0, stream>>>(act, wdn, cnts, yb);
  k_combine<<<dim3(T_TOK),            dim3(256), 0, stream>>>(yb, topk_idx, topk_w, pair_pos, out);
}